// Round 15
// baseline (95.706 us; speedup 1.0000x reference)
//
#include <hip/hip_runtime.h>
#include <hip/hip_bf16.h>
#include <math.h>

#define N 4096
#define D 128
#define R 16  // rows per block (one 16-row m-tile)
#define PF 8  // register prefetch depth (n-tiles in flight)
#define POS_W 2.0f
#define NEG_W 40.0f
#define MARGIN 0.1f
#define THRESH 0.5f

typedef __bf16 bf16x8 __attribute__((ext_vector_type(8)));
typedef float f32x4 __attribute__((ext_vector_type(4)));

// Packed operand layout (ushort units), group stride 2048 (= 16 rows x 128 k):
//   xp[g][ks][lane][e] -> g*2048 + ks*512 + lane*8 + e
// g = row>>4, lane = lk*16 + lr (lr=row&15), element (row,k): k = ks*32+lk*8+e.
// A wave's MFMA fragment for (g, ks) is ONE contiguous 1KB load: base+lane*16B.

// ---------------- K1: L2-normalize rows -> bf16, write MFMA-packed layout ----------------
__global__ __launch_bounds__(512) void k_norm(const float* __restrict__ x,
                                              ushort* __restrict__ xp) {
  const int t = threadIdx.x, wv = t >> 6, lane = t & 63;
#pragma unroll
  for (int rr = 0; rr < 2; ++rr) {
    const int row = blockIdx.x * 16 + wv * 2 + rr;
    const float2 v = *(const float2*)&x[row * D + lane * 2];
    float ss = v.x * v.x + v.y * v.y;
#pragma unroll
    for (int off = 32; off; off >>= 1) ss += __shfl_xor(ss, off);
    const float rnorm = rsqrtf(ss);
    __hip_bfloat162 o;
    o.x = __float2bfloat16(v.x * rnorm);
    o.y = __float2bfloat16(v.y * rnorm);
    // k0 = lane*2: ks = lane>>4, lk = (lane&15)>>2, e = (lane&3)*2
    const int g = row >> 4, lr = row & 15;
    const int ks = lane >> 4, lk = (lane >> 2) & 3, e = (lane & 3) * 2;
    const int idx = g * 2048 + ks * 512 + (lk * 16 + lr) * 8 + e;
    *(__hip_bfloat162*)&xp[idx] = o;
  }
}

// ---------------- K2: full row-stripe per block; 8-deep B-prefetch pipeline ----------------
// Block b owns rows i0=b*16 .. i0+15 vs ALL N cols. Wave wv owns cols wv*512..+511.
// S stripe stays in registers across both mining phases. No cross-block deps.
__global__ __launch_bounds__(512, 2) void k_mega(const ushort* __restrict__ xp,
                                                 const int* __restrict__ labels,
                                                 float* __restrict__ row_pos,
                                                 float* __restrict__ row_neg,
                                                 float* __restrict__ row_valid) {
  __shared__ int labs[N];  // 16 KB: all labels
  __shared__ float redA[8][R], redB[8][R];
  __shared__ float mpS[R], mnS[R];

  const int t = threadIdx.x;
  const int wv = t >> 6, lane = t & 63;
  const int lk = lane >> 4, lr = lane & 15;
  const int i0 = blockIdx.x * R;

  // stage all labels into LDS (coalesced int4)
#pragma unroll
  for (int it = 0; it < 2; ++it)
    ((int4*)labs)[t + it * 512] = ((const int4*)labels)[t + it * 512];
  __syncthreads();

  // A fragments: group g = blockIdx.x; one contiguous 1KB wave-load per ks
  bf16x8 af[4];
#pragma unroll
  for (int ks = 0; ks < 4; ++ks)
    af[ks] = *(const bf16x8*)&xp[blockIdx.x * 2048 + ks * 512 + lane * 8];

  // ---- matmul: 32 n-tiles x 4 k-steps; explicit PF-deep prefetch ----
  const int jbase = wv * 512 + lr;  // lane's B-row for n-tile n: jbase + n*16
  const ushort* bbase = &xp[(size_t)(wv * 32) * 2048 + lane * 8];

  bf16x8 bf[PF][4];
#pragma unroll
  for (int p = 0; p < PF; ++p)
#pragma unroll
    for (int ks = 0; ks < 4; ++ks)
      bf[p][ks] = *(const bf16x8*)(bbase + p * 2048 + ks * 512);

  f32x4 acc[32];
#pragma unroll
  for (int n = 0; n < 32; ++n) acc[n] = (f32x4){0.f, 0.f, 0.f, 0.f};

#pragma unroll
  for (int n = 0; n < 32; ++n) {
    const int s = n & (PF - 1);  // compile-time after unroll
    acc[n] = __builtin_amdgcn_mfma_f32_16x16x32_bf16(af[0], bf[s][0], acc[n], 0, 0, 0);
    acc[n] = __builtin_amdgcn_mfma_f32_16x16x32_bf16(af[1], bf[s][1], acc[n], 0, 0, 0);
    acc[n] = __builtin_amdgcn_mfma_f32_16x16x32_bf16(af[2], bf[s][2], acc[n], 0, 0, 0);
    acc[n] = __builtin_amdgcn_mfma_f32_16x16x32_bf16(af[3], bf[s][3], acc[n], 0, 0, 0);
    if (n < 32 - PF) {
#pragma unroll
      for (int ks = 0; ks < 4; ++ks)
        bf[s][ks] = *(const bf16x8*)(bbase + (n + PF) * 2048 + ks * 512);
    }
  }

  // C layout: col = lr (B-row), rows = lk*4 + r (A-rows), r = reg 0..3
  int labr[4];
  int girow[4];
#pragma unroll
  for (int r = 0; r < 4; ++r) {
    girow[r] = i0 + lk * 4 + r;
    labr[r] = labs[girow[r]];
  }

  // ---- phase 1: per-row min_pos / max_neg (block-local) ----
  float pmin[4] = {1e9f, 1e9f, 1e9f, 1e9f};
  float nmax[4] = {-1e9f, -1e9f, -1e9f, -1e9f};
#pragma unroll
  for (int n = 0; n < 32; ++n) {
    const int j = jbase + n * 16;
    const int lj = labs[j];
#pragma unroll
    for (int r = 0; r < 4; ++r) {
      const float s = acc[n][r];
      if (lj == labr[r]) {
        if (girow[r] != j) pmin[r] = fminf(pmin[r], s);
      } else {
        nmax[r] = fmaxf(nmax[r], s);
      }
    }
  }
#pragma unroll
  for (int o = 1; o < 16; o <<= 1) {
#pragma unroll
    for (int r = 0; r < 4; ++r) {
      pmin[r] = fminf(pmin[r], __shfl_xor(pmin[r], o));
      nmax[r] = fmaxf(nmax[r], __shfl_xor(nmax[r], o));
    }
  }
  if (lr == 0) {
#pragma unroll
    for (int r = 0; r < 4; ++r) {
      redA[wv][lk * 4 + r] = pmin[r];
      redB[wv][lk * 4 + r] = nmax[r];
    }
  }
  __syncthreads();
  if (t < R) {
    float mp = 1e9f, mx = -1e9f;
#pragma unroll
    for (int wvv = 0; wvv < 8; ++wvv) {
      mp = fminf(mp, redA[wvv][t]);
      mx = fmaxf(mx, redB[wvv][t]);
    }
    mpS[t] = mp;
    mnS[t] = mx;
  }
  __syncthreads();

  // ---- phase 2: mined exp sums over the SAME registers ----
  float mpr[4], mxr[4];
#pragma unroll
  for (int r = 0; r < 4; ++r) {
    mpr[r] = mpS[lk * 4 + r];
    mxr[r] = mnS[lk * 4 + r];
  }
  float psum[4] = {0.f, 0.f, 0.f, 0.f};
  float nsum[4] = {0.f, 0.f, 0.f, 0.f};
#pragma unroll
  for (int n = 0; n < 32; ++n) {
    const int j = jbase + n * 16;
    const int lj = labs[j];
#pragma unroll
    for (int r = 0; r < 4; ++r) {
      const float s = acc[n][r];
      if (lj == labr[r]) {
        if ((girow[r] != j) && (s - MARGIN < mxr[r])) psum[r] += __expf(-POS_W * (s - THRESH));
      } else {
        if (s + MARGIN > mpr[r]) nsum[r] += __expf(NEG_W * (s - THRESH));
      }
    }
  }
#pragma unroll
  for (int o = 1; o < 16; o <<= 1) {
#pragma unroll
    for (int r = 0; r < 4; ++r) {
      psum[r] += __shfl_xor(psum[r], o);
      nsum[r] += __shfl_xor(nsum[r], o);
    }
  }
  if (lr == 0) {
#pragma unroll
    for (int r = 0; r < 4; ++r) {
      redA[wv][lk * 4 + r] = psum[r];
      redB[wv][lk * 4 + r] = nsum[r];
    }
  }
  __syncthreads();

  // ---- row terms (block-local) ----
  if (t < R) {
    float ps = 0.f, ns = 0.f;
#pragma unroll
    for (int wvv = 0; wvv < 8; ++wvv) {
      ps += redA[wvv][t];
      ns += redB[wvv][t];
    }
    const float mp = mpS[t], mx = mnS[t];
    const bool valid = (mp < 1e8f) && (mx > -1e8f) && (ps > 0.f) && (ns > 0.f);
    row_pos[i0 + t] = valid ? (log1pf(ps) * (1.0f / POS_W)) : 0.f;
    row_neg[i0 + t] = valid ? (log1pf(ns) * (1.0f / NEG_W)) : 0.f;
    row_valid[i0 + t] = valid ? 1.f : 0.f;
  }
}

// ---------------- K3: final reduction ----------------
__global__ __launch_bounds__(256) void k_final(const float* __restrict__ rp,
                                               const float* __restrict__ rn,
                                               const float* __restrict__ rv,
                                               float* __restrict__ out) {
  __shared__ float red[3][4];
  const int t = threadIdx.x, wv = t >> 6, lane = t & 63;
  float sp = 0.f, sn = 0.f, sc = 0.f;
  for (int i = t; i < N; i += 256) { sp += rp[i]; sn += rn[i]; sc += rv[i]; }
#pragma unroll
  for (int off = 32; off; off >>= 1) {
    sp += __shfl_xor(sp, off);
    sn += __shfl_xor(sn, off);
    sc += __shfl_xor(sc, off);
  }
  if (lane == 0) { red[0][wv] = sp; red[1][wv] = sn; red[2][wv] = sc; }
  __syncthreads();
  if (t == 0) {
    const float tp = red[0][0] + red[0][1] + red[0][2] + red[0][3];
    const float tn = red[1][0] + red[1][1] + red[1][2] + red[1][3];
    const float tc = red[2][0] + red[2][1] + red[2][2] + red[2][3];
    const float cnt = fmaxf(tc, 1.f);
    const float pm = tp / cnt, nm = tn / cnt;
    out[0] = pm + nm;
    out[1] = pm;
    out[2] = nm;
  }
}

extern "C" void kernel_launch(void* const* d_in, const int* in_sizes, int n_in,
                              void* d_out, int out_size, void* d_ws, size_t ws_size,
                              hipStream_t stream) {
  const float* batch = (const float*)d_in[0];
  const int* labels = (const int*)d_in[1];
  float* out = (float*)d_out;

  char* ws = (char*)d_ws;
  ushort* xp = (ushort*)ws;  // packed operands: N*D bf16 = 1 MB (stride-2048 groups)
  // outputs placed well past xp (defensive 4 MB offset; no overlap possible)
  float* row_pos = (float*)(ws + (size_t)4 * 1024 * 1024);
  float* row_neg = row_pos + N;
  float* row_valid = row_neg + N;

  k_norm<<<N / 16, 512, 0, stream>>>(batch, xp);
  k_mega<<<N / R, 512, 0, stream>>>(xp, labels, row_pos, row_neg, row_valid);
  k_final<<<1, 256, 0, stream>>>(row_pos, row_neg, row_valid, out);
}

// Round 16
// 84.624 us; speedup vs baseline: 1.1309x; 1.1309x over previous
//
#include <hip/hip_runtime.h>
#include <hip/hip_bf16.h>
#include <math.h>

#define N 4096
#define D 128
#define R 16  // rows per block (one 16-row m-tile)
#define POS_W 2.0f
#define NEG_W 40.0f
#define MARGIN 0.1f
#define THRESH 0.5f

typedef __bf16 bf16x8 __attribute__((ext_vector_type(8)));
typedef float f32x4 __attribute__((ext_vector_type(4)));

// Packed operand layout (ushort units), group stride 2048 (= 16 rows x 128 k):
//   xp[g][ks][lane][e] -> g*2048 + ks*512 + lane*8 + e
// g = row>>4, lane = lk*16 + lr (lr=row&15), element (row,k): k = ks*32+lk*8+e.
// A wave's MFMA fragment for (g, ks) is ONE contiguous 1KB load: base+lane*16B.

// ---------------- K1: L2-normalize rows -> bf16, write MFMA-packed layout ----------------
__global__ __launch_bounds__(512) void k_norm(const float* __restrict__ x,
                                              ushort* __restrict__ xp) {
  const int t = threadIdx.x, wv = t >> 6, lane = t & 63;
#pragma unroll
  for (int rr = 0; rr < 2; ++rr) {
    const int row = blockIdx.x * 16 + wv * 2 + rr;
    const float2 v = *(const float2*)&x[row * D + lane * 2];
    float ss = v.x * v.x + v.y * v.y;
#pragma unroll
    for (int off = 32; off; off >>= 1) ss += __shfl_xor(ss, off);
    const float rnorm = rsqrtf(ss);
    __hip_bfloat162 o;
    o.x = __float2bfloat16(v.x * rnorm);
    o.y = __float2bfloat16(v.y * rnorm);
    // k0 = lane*2: ks = lane>>4, lk = (lane&15)>>2, e = (lane&3)*2
    const int g = row >> 4, lr = row & 15;
    const int ks = lane >> 4, lk = (lane >> 2) & 3, e = (lane & 3) * 2;
    const int idx = g * 2048 + ks * 512 + (lk * 16 + lr) * 8 + e;
    *(__hip_bfloat162*)&xp[idx] = o;
  }
}

// ---------------- K2: full row-stripe per block; 16 waves (1024 thr), TLP-hidden loads ----
// Block b owns rows i0=b*16 .. i0+15 vs ALL N cols. Wave wv owns cols wv*256..+255.
// 4 waves/SIMD; acc[16] = 64 VGPR so the whole wave fits <=128 VGPR.
__global__ __launch_bounds__(1024) void k_mega(const ushort* __restrict__ xp,
                                               const int* __restrict__ labels,
                                               float* __restrict__ row_pos,
                                               float* __restrict__ row_neg,
                                               float* __restrict__ row_valid) {
  __shared__ int labs[N];  // 16 KB: all labels
  __shared__ float redA[16][R], redB[16][R];
  __shared__ float mpS[R], mnS[R];

  const int t = threadIdx.x;
  const int wv = t >> 6, lane = t & 63;
  const int lk = lane >> 4, lr = lane & 15;
  const int i0 = blockIdx.x * R;

  // stage all labels into LDS (coalesced int4; 1024 threads x 1 int4)
  ((int4*)labs)[t] = ((const int4*)labels)[t];
  __syncthreads();

  // A fragments: group g = blockIdx.x; one contiguous 1KB wave-load per ks
  bf16x8 af[4];
#pragma unroll
  for (int ks = 0; ks < 4; ++ks)
    af[ks] = *(const bf16x8*)&xp[blockIdx.x * 2048 + ks * 512 + lane * 8];

  // ---- matmul: 16 n-tiles x 4 k-steps; loads hidden by 4-waves/SIMD TLP ----
  const int jbase = wv * 256 + lr;  // lane's B-row for n-tile n: jbase + n*16
  const ushort* bbase = &xp[(size_t)(wv * 16) * 2048 + lane * 8];

  f32x4 acc[16];
#pragma unroll
  for (int n = 0; n < 16; ++n) acc[n] = (f32x4){0.f, 0.f, 0.f, 0.f};

#pragma unroll
  for (int n = 0; n < 16; ++n) {
    const ushort* bp = bbase + n * 2048;
    const bf16x8 b0 = *(const bf16x8*)(bp);
    const bf16x8 b1 = *(const bf16x8*)(bp + 512);
    const bf16x8 b2 = *(const bf16x8*)(bp + 1024);
    const bf16x8 b3 = *(const bf16x8*)(bp + 1536);
    acc[n] = __builtin_amdgcn_mfma_f32_16x16x32_bf16(af[0], b0, acc[n], 0, 0, 0);
    acc[n] = __builtin_amdgcn_mfma_f32_16x16x32_bf16(af[1], b1, acc[n], 0, 0, 0);
    acc[n] = __builtin_amdgcn_mfma_f32_16x16x32_bf16(af[2], b2, acc[n], 0, 0, 0);
    acc[n] = __builtin_amdgcn_mfma_f32_16x16x32_bf16(af[3], b3, acc[n], 0, 0, 0);
  }

  // C layout: col = lr (B-row), rows = lk*4 + r (A-rows), r = reg 0..3
  int labr[4];
  int girow[4];
#pragma unroll
  for (int r = 0; r < 4; ++r) {
    girow[r] = i0 + lk * 4 + r;
    labr[r] = labs[girow[r]];
  }

  // ---- phase 1: per-row min_pos / max_neg (block-local) ----
  float pmin[4] = {1e9f, 1e9f, 1e9f, 1e9f};
  float nmax[4] = {-1e9f, -1e9f, -1e9f, -1e9f};
#pragma unroll
  for (int n = 0; n < 16; ++n) {
    const int j = jbase + n * 16;
    const int lj = labs[j];
#pragma unroll
    for (int r = 0; r < 4; ++r) {
      const float s = acc[n][r];
      if (lj == labr[r]) {
        if (girow[r] != j) pmin[r] = fminf(pmin[r], s);
      } else {
        nmax[r] = fmaxf(nmax[r], s);
      }
    }
  }
#pragma unroll
  for (int o = 1; o < 16; o <<= 1) {
#pragma unroll
    for (int r = 0; r < 4; ++r) {
      pmin[r] = fminf(pmin[r], __shfl_xor(pmin[r], o));
      nmax[r] = fmaxf(nmax[r], __shfl_xor(nmax[r], o));
    }
  }
  if (lr == 0) {
#pragma unroll
    for (int r = 0; r < 4; ++r) {
      redA[wv][lk * 4 + r] = pmin[r];
      redB[wv][lk * 4 + r] = nmax[r];
    }
  }
  __syncthreads();
  if (t < R) {
    float mp = 1e9f, mx = -1e9f;
#pragma unroll
    for (int wvv = 0; wvv < 16; ++wvv) {
      mp = fminf(mp, redA[wvv][t]);
      mx = fmaxf(mx, redB[wvv][t]);
    }
    mpS[t] = mp;
    mnS[t] = mx;
  }
  __syncthreads();

  // ---- phase 2: mined exp sums over the SAME registers ----
  float mpr[4], mxr[4];
#pragma unroll
  for (int r = 0; r < 4; ++r) {
    mpr[r] = mpS[lk * 4 + r];
    mxr[r] = mnS[lk * 4 + r];
  }
  float psum[4] = {0.f, 0.f, 0.f, 0.f};
  float nsum[4] = {0.f, 0.f, 0.f, 0.f};
#pragma unroll
  for (int n = 0; n < 16; ++n) {
    const int j = jbase + n * 16;
    const int lj = labs[j];
#pragma unroll
    for (int r = 0; r < 4; ++r) {
      const float s = acc[n][r];
      if (lj == labr[r]) {
        if ((girow[r] != j) && (s - MARGIN < mxr[r])) psum[r] += __expf(-POS_W * (s - THRESH));
      } else {
        if (s + MARGIN > mpr[r]) nsum[r] += __expf(NEG_W * (s - THRESH));
      }
    }
  }
#pragma unroll
  for (int o = 1; o < 16; o <<= 1) {
#pragma unroll
    for (int r = 0; r < 4; ++r) {
      psum[r] += __shfl_xor(psum[r], o);
      nsum[r] += __shfl_xor(nsum[r], o);
    }
  }
  if (lr == 0) {
#pragma unroll
    for (int r = 0; r < 4; ++r) {
      redA[wv][lk * 4 + r] = psum[r];
      redB[wv][lk * 4 + r] = nsum[r];
    }
  }
  __syncthreads();

  // ---- row terms (block-local) ----
  if (t < R) {
    float ps = 0.f, ns = 0.f;
#pragma unroll
    for (int wvv = 0; wvv < 16; ++wvv) {
      ps += redA[wvv][t];
      ns += redB[wvv][t];
    }
    const float mp = mpS[t], mx = mnS[t];
    const bool valid = (mp < 1e8f) && (mx > -1e8f) && (ps > 0.f) && (ns > 0.f);
    row_pos[i0 + t] = valid ? (log1pf(ps) * (1.0f / POS_W)) : 0.f;
    row_neg[i0 + t] = valid ? (log1pf(ns) * (1.0f / NEG_W)) : 0.f;
    row_valid[i0 + t] = valid ? 1.f : 0.f;
  }
}

// ---------------- K3: final reduction ----------------
__global__ __launch_bounds__(256) void k_final(const float* __restrict__ rp,
                                               const float* __restrict__ rn,
                                               const float* __restrict__ rv,
                                               float* __restrict__ out) {
  __shared__ float red[3][4];
  const int t = threadIdx.x, wv = t >> 6, lane = t & 63;
  float sp = 0.f, sn = 0.f, sc = 0.f;
  for (int i = t; i < N; i += 256) { sp += rp[i]; sn += rn[i]; sc += rv[i]; }
#pragma unroll
  for (int off = 32; off; off >>= 1) {
    sp += __shfl_xor(sp, off);
    sn += __shfl_xor(sn, off);
    sc += __shfl_xor(sc, off);
  }
  if (lane == 0) { red[0][wv] = sp; red[1][wv] = sn; red[2][wv] = sc; }
  __syncthreads();
  if (t == 0) {
    const float tp = red[0][0] + red[0][1] + red[0][2] + red[0][3];
    const float tn = red[1][0] + red[1][1] + red[1][2] + red[1][3];
    const float tc = red[2][0] + red[2][1] + red[2][2] + red[2][3];
    const float cnt = fmaxf(tc, 1.f);
    const float pm = tp / cnt, nm = tn / cnt;
    out[0] = pm + nm;
    out[1] = pm;
    out[2] = nm;
  }
}

extern "C" void kernel_launch(void* const* d_in, const int* in_sizes, int n_in,
                              void* d_out, int out_size, void* d_ws, size_t ws_size,
                              hipStream_t stream) {
  const float* batch = (const float*)d_in[0];
  const int* labels = (const int*)d_in[1];
  float* out = (float*)d_out;

  char* ws = (char*)d_ws;
  ushort* xp = (ushort*)ws;  // packed operands: N*D bf16 = 1 MB (stride-2048 groups)
  // outputs placed well past xp (defensive 4 MB offset; no overlap possible)
  float* row_pos = (float*)(ws + (size_t)4 * 1024 * 1024);
  float* row_neg = row_pos + N;
  float* row_valid = row_neg + N;

  k_norm<<<N / 16, 512, 0, stream>>>(batch, xp);
  k_mega<<<N / R, 1024, 0, stream>>>(xp, labels, row_pos, row_neg, row_valid);
  k_final<<<1, 256, 0, stream>>>(row_pos, row_neg, row_valid, out);
}